// Round 8
// baseline (298.037 us; speedup 1.0000x reference)
//
#include <hip/hip_runtime.h>
#include <hip/hip_bf16.h>
#include <stdint.h>

#define B_ 4
#define N_ 2048
#define DIM_ 512
#define H_ 8
#define D_ 64
#define M_ (B_*N_)   // 8192

typedef unsigned short u16;
typedef short bf16x8 __attribute__((ext_vector_type(8)));
typedef float f32x4 __attribute__((ext_vector_type(4)));
typedef float f32x16 __attribute__((ext_vector_type(16)));
typedef unsigned short u16x8 __attribute__((ext_vector_type(8)));
typedef unsigned short u16x4 __attribute__((ext_vector_type(4)));

__device__ __forceinline__ u16 f2bf(float f) {
  union { float f; uint32_t u; } v; v.f = f;
  uint32_t r = v.u + 0x7fffu + ((v.u >> 16) & 1u);
  return (u16)(r >> 16);
}

__device__ __forceinline__ void gload_lds16(const void* g, void* l) {
  __builtin_amdgcn_global_load_lds(
      (const __attribute__((address_space(1))) void*)g,
      (__attribute__((address_space(3))) void*)l, 16, 0, 0);
}

__device__ __forceinline__ uint32_t cvt_pk(float a, float b) {
  uint32_t r;
  asm("v_cvt_pk_bf16_f32 %0, %1, %2" : "=v"(r) : "v"(a), "v"(b));
  return r;
}

// swaps upper 32 lanes of a with lower 32 lanes of b
__device__ __forceinline__ void swap32(uint32_t &a, uint32_t &b) {
  asm("v_permlane32_swap_b32 %0, %1" : "+v"(a), "+v"(b));
}

__device__ __forceinline__ bf16x8 mkfrag(uint32_t w0, uint32_t w1, uint32_t w2, uint32_t w3) {
  union { uint32_t u[4]; bf16x8 v; } x;
  x.u[0]=w0; x.u[1]=w1; x.u[2]=w2; x.u[3]=w3;
  return x.v;
}

// ---------------- fused: x -> xb bf16 [8192][512]  AND  x -> vt[bh][d][n] bf16 ----------------
__global__ __launch_bounds__(256) void k_prep_x(const float* __restrict__ x,
                                                u16* __restrict__ xb,
                                                u16* __restrict__ vt) {
  __shared__ float ts[64][65];
  int nt = blockIdx.x;   // 0..31  (n tile of 64)
  int h  = blockIdx.y;   // 0..7
  int b  = blockIdx.z;   // 0..3
  int t = threadIdx.x;
  int n0 = nt * 64;
  int r16 = t >> 4;         // 0..15
  int c4  = (t & 15) * 4;   // 0..60
#pragma unroll
  for (int rep = 0; rep < 4; ++rep) {
    int n_loc = rep*16 + r16;
    size_t row = (size_t)(b*N_ + n0 + n_loc);
    float4 v = *(const float4*)(x + row*DIM_ + h*64 + c4);
    ts[n_loc][c4+0]=v.x; ts[n_loc][c4+1]=v.y; ts[n_loc][c4+2]=v.z; ts[n_loc][c4+3]=v.w;
    u16x4 o; o[0]=f2bf(v.x); o[1]=f2bf(v.y); o[2]=f2bf(v.z); o[3]=f2bf(v.w);
    *(u16x4*)(xb + row*DIM_ + h*64 + c4) = o;
  }
  __syncthreads();
#pragma unroll
  for (int rep = 0; rep < 4; ++rep) {
    int d_loc = rep*16 + r16;
    u16x4 o;
#pragma unroll
    for (int i = 0; i < 4; ++i) o[i] = f2bf(ts[c4+i][d_loc]);
    *(u16x4*)(vt + (size_t)((b*H_+h)*64 + d_loc)*N_ + n0 + c4) = o;
  }
}

// ---------------- convert Wq/Wk -> bf16 ----------------
__global__ __launch_bounds__(256) void k_convert_w(const float* __restrict__ Wq,
                                                   const float* __restrict__ Wk,
                                                   u16* __restrict__ wqb,
                                                   u16* __restrict__ wkb) {
  int t = blockIdx.x * 256 + threadIdx.x;
  int e = t * 8;
  const float* src; u16* dst; int off;
  if (e < DIM_*DIM_) { src = Wq; dst = wqb; off = e; }
  else               { src = Wk; dst = wkb; off = e - DIM_*DIM_; }
  const float4* p = (const float4*)(src + off);
  float4 a = p[0], b = p[1];
  u16x8 o;
  o[0]=f2bf(a.x); o[1]=f2bf(a.y); o[2]=f2bf(a.z); o[3]=f2bf(a.w);
  o[4]=f2bf(b.x); o[5]=f2bf(b.y); o[6]=f2bf(b.z); o[7]=f2bf(b.w);
  *(u16x8*)(dst + off) = o;
}

// ---------------- projection GEMM: [8192x512] = xb @ W^T, store head-major ----------------
__global__ __launch_bounds__(256) void k_gemm_qk(const u16* __restrict__ xb,
                                                 const u16* __restrict__ wqb,
                                                 const u16* __restrict__ wkb,
                                                 u16* __restrict__ qb,
                                                 u16* __restrict__ kb) {
  __shared__ __align__(16) u16 As[128*64];
  __shared__ __align__(16) u16 Bs[128*64];
  int mt = blockIdx.x, ntile = blockIdx.y, z = blockIdx.z;
  const u16* Bw = z ? wkb : wqb;
  u16* C = z ? kb : qb;
  float scale = z ? 1.0f : 0.125f;
  int tid = threadIdx.x, lane = tid & 63, w = tid >> 6;
  int wr = w >> 1, wc = w & 1;
  int lr = lane >> 3, lc8 = lane & 7;
  int l4 = lane >> 4, l15 = lane & 15;

  f32x4 acc[4][4] = {};

  const u16* Abase = xb + (size_t)(mt*128)*DIM_;
  const u16* Bbase = Bw + (size_t)(ntile*128)*DIM_;

  for (int kk = 0; kk < 8; ++kk) {
#pragma unroll
    for (int i = 0; i < 4; ++i) {
      int rowl = w*32 + i*8 + lr;
      int cbs = lc8 ^ (rowl & 7);
      gload_lds16(Abase + (size_t)rowl*DIM_ + kk*64 + cbs*8, As + (w*32 + i*8)*64);
      gload_lds16(Bbase + (size_t)rowl*DIM_ + kk*64 + cbs*8, Bs + (w*32 + i*8)*64);
    }
    __syncthreads();
#pragma unroll
    for (int kc = 0; kc < 2; ++kc) {
      bf16x8 af[4], bfr[4];
#pragma unroll
      for (int i = 0; i < 4; ++i) {
        int row = wr*64 + i*16 + l15;
        int cb = (kc*4 + l4) ^ (row & 7);
        af[i] = *(const bf16x8*)(As + row*64 + cb*8);
      }
#pragma unroll
      for (int j = 0; j < 4; ++j) {
        int row = wc*64 + j*16 + l15;
        int cb = (kc*4 + l4) ^ (row & 7);
        bfr[j] = *(const bf16x8*)(Bs + row*64 + cb*8);
      }
#pragma unroll
      for (int i = 0; i < 4; ++i)
#pragma unroll
        for (int j = 0; j < 4; ++j)
          acc[i][j] = __builtin_amdgcn_mfma_f32_16x16x32_bf16(af[i], bfr[j], acc[i][j], 0, 0, 0);
    }
    __syncthreads();
  }
#pragma unroll
  for (int i = 0; i < 4; ++i) {
#pragma unroll
    for (int j = 0; j < 4; ++j) {
#pragma unroll
      for (int r = 0; r < 4; ++r) {
        int m = mt*128 + wr*64 + i*16 + l4*4 + r;
        int o = ntile*128 + wc*64 + j*16 + l15;
        u16 v = f2bf(acc[i][j][r] * scale);
        C[(size_t)((m >> 11)*H_ + (o >> 6))*(N_*64) + (size_t)(m & (N_-1))*64 + (o & 63)] = v;
      }
    }
  }
}

// ---------------- attention: out = tanh(q k^T) v ----------------
// grid 512 blocks (xcd-chunked), 1024 threads = 16 waves = 4 qsub x 4 kv-groups.
// Block = (bh, qt of 128 rows). Wave (w4, grp): q rows qt*128+w4*32, kv quarter
// grp*512, KVBLK=32, dbuf LDS per grp. 2 blocks/CU -> 32 waves/CU (full occ).
// 4-way partial-O reduce through reused tile LDS.
__global__ __launch_bounds__(1024, 8) void k_attn(const u16* __restrict__ qb,
                                                  const u16* __restrict__ kb,
                                                  const u16* __restrict__ vt,
                                                  float* __restrict__ out) {
  __shared__ __align__(16) u16 TK[4][2][32*64];  // 32 KB: K tiles [kv32][d64]
  __shared__ __align__(16) u16 TV[4][2][64*32];  // 32 KB: V tiles [d64][kv32]
  int wg = blockIdx.x;
  int xcd = wg & 7, local = wg >> 3;       // local 0..63
  int bh = (xcd << 2) | (local >> 4);      // 4 bh per XCD -> K/V L2-resident
  int qt = local & 15;                     // 0..15, 128 q rows
  int tid = threadIdx.x, lane = tid & 63, w = tid >> 6;   // w 0..15
  int w4 = w & 3, grp = w >> 2;            // q sub-tile / kv quarter
  int l31 = lane & 31, hi = lane >> 5;
  int qrow = qt*128 + w4*32 + l31;

  const char* kbh = (const char*)(kb + (size_t)bh*N_*64);
  const char* vbh = (const char*)(vt + (size_t)bh*64*N_);

  // Q fragments (B-operand rows): Q[q=l31][d = c*16 + hi*8 ..+8]
  const u16* qp = qb + ((size_t)bh*N_ + qrow)*64 + hi*8;
  bf16x8 qf[4];
#pragma unroll
  for (int c = 0; c < 4; ++c) qf[c] = *(const bf16x8*)(qp + c*16);

  // staging geometry (per wave: 1KB of its grp's K tile + 1KB of V tile)
  int krow_s = (lane >> 3);                 // 0..7 ; global K row = w4*8 + krow_s
  int kcol_s = ((lane & 7) ^ krow_s) * 16;  // inverse-swizzled source col (row&7==krow_s)
  int vrow_s = w4*16 + (lane >> 2);         // 0..63 (d)
  int vswz_s = (vrow_s ^ (vrow_s >> 2)) & 3;
  int vcol_s = ((lane & 3) ^ vswz_s) * 16;
  int kvb = grp * 512;

#define STAGE(buf, jt_) do { \
    gload_lds16(kbh + (size_t)(kvb + (jt_)*32 + w4*8 + krow_s)*128 + kcol_s, \
                &TK[grp][buf][w4*512]); \
    gload_lds16(vbh + (size_t)vrow_s*(N_*2) + (size_t)(kvb + (jt_)*32)*2 + vcol_s, \
                &TV[grp][buf][w4*512]); \
  } while (0)

  int rswk = (l31 & 7) << 4;                // K read swizzle
  int rswv = (l31 ^ (l31 >> 2)) & 3;        // V read swizzle (dhalf-independent)

  f32x16 acc_o0 = {};
  f32x16 acc_o1 = {};

  STAGE(0, 0);
  __syncthreads();

  for (int jt = 0; jt < 16; ++jt) {
    int cur = jt & 1;
    if (jt < 15) STAGE(cur ^ 1, jt + 1);

    const char* Kt = (const char*)&TK[grp][cur][0];
    const char* Vt = (const char*)&TV[grp][cur][0];

    // K fragments: K[kv=l31][d = c*16 + hi*8]
    bf16x8 ka[4];
#pragma unroll
    for (int c = 0; c < 4; ++c)
      ka[c] = *(const bf16x8*)(Kt + l31*128 + ((c*32 + hi*16) ^ rswk));
    // S^T tile: rows = kv (crow(r,hi)), cols = q (l31)
    f32x16 st = {};
    __builtin_amdgcn_s_setprio(1);
#pragma unroll
    for (int c = 0; c < 4; ++c)
      st = __builtin_amdgcn_mfma_f32_32x32x16_bf16(ka[c], qf[c], st, 0, 0, 0);
    __builtin_amdgcn_s_setprio(0);
    // tanh in-register
    float p[16];
#pragma unroll
    for (int r = 0; r < 16; ++r) {
      float e = __builtin_amdgcn_exp2f(st[r] * 2.8853900817779268f);
      p[r] = 1.0f - 2.0f * __builtin_amdgcn_rcpf(e + 1.0f);
    }
    // pack to PV A-fragments: word w holds kv = ks*16 + hi*8 + {2w,2w+1}
    uint32_t a0 = cvt_pk(p[0], p[1]),   b0 = cvt_pk(p[4], p[5]);
    uint32_t a1 = cvt_pk(p[2], p[3]),   b1 = cvt_pk(p[6], p[7]);
    swap32(a0, b0); swap32(a1, b1);
    uint32_t a2 = cvt_pk(p[8], p[9]),   b2 = cvt_pk(p[12], p[13]);
    uint32_t a3 = cvt_pk(p[10], p[11]), b3 = cvt_pk(p[14], p[15]);
    swap32(a2, b2); swap32(a3, b3);
    bf16x8 pa0 = mkfrag(a0, a1, b0, b1);   // kv 0..15
    bf16x8 pa1 = mkfrag(a2, a3, b2, b3);   // kv 16..31
    // O += P V : A = P rows (q), B = V rows read as [d][kv]
    __builtin_amdgcn_s_setprio(1);
#pragma unroll
    for (int kc = 0; kc < 2; ++kc) {
      bf16x8 pv = kc ? pa1 : pa0;
      int cb = ((kc*2 + hi) ^ rswv) * 16;
      bf16x8 v0 = *(const bf16x8*)(Vt + (     l31)*64 + cb);
      bf16x8 v1 = *(const bf16x8*)(Vt + (32 + l31)*64 + cb);
      acc_o0 = __builtin_amdgcn_mfma_f32_32x32x16_bf16(pv, v0, acc_o0, 0, 0, 0);
      acc_o1 = __builtin_amdgcn_mfma_f32_32x32x16_bf16(pv, v1, acc_o1, 0, 0, 0);
    }
    __builtin_amdgcn_s_setprio(0);
    __syncthreads();   // staged loads drained before next iteration
  }

  // 4-way combine via reused tile LDS (two 32KB regions)
  float* redA = (float*)&TK[0][0][0];
  float* redB = (float*)&TV[0][0][0];
  // stage 1: grp1 -> A, grp3 -> B
  if (grp == 1 || grp == 3) {
    float* R = (grp == 1) ? redA : redB;
#pragma unroll
    for (int r = 0; r < 16; ++r) {
      int row = 4*hi + (r & 3) + 8*(r >> 2);
      R[(w4*32 + row)*64 + l31]      = acc_o0[r];
      R[(w4*32 + row)*64 + l31 + 32] = acc_o1[r];
    }
  }
  __syncthreads();
  if (grp == 0 || grp == 2) {
    const float* R = (grp == 0) ? redA : redB;
#pragma unroll
    for (int r = 0; r < 16; ++r) {
      int row = 4*hi + (r & 3) + 8*(r >> 2);
      acc_o0[r] += R[(w4*32 + row)*64 + l31];
      acc_o1[r] += R[(w4*32 + row)*64 + l31 + 32];
    }
  }
  __syncthreads();
  // stage 2: grp2 -> A
  if (grp == 2) {
#pragma unroll
    for (int r = 0; r < 16; ++r) {
      int row = 4*hi + (r & 3) + 8*(r >> 2);
      redA[(w4*32 + row)*64 + l31]      = acc_o0[r];
      redA[(w4*32 + row)*64 + l31 + 32] = acc_o1[r];
    }
  }
  __syncthreads();
  if (grp == 0) {
    int b = bh >> 3, h = bh & 7;
    int q0 = qt*128 + w4*32 + 4*hi;
    float* ob = out + (size_t)b*N_*DIM_ + h*64 + l31;
#pragma unroll
    for (int r = 0; r < 16; ++r) {
      int row = 4*hi + (r & 3) + 8*(r >> 2);
      int q = q0 + (r & 3) + 8*(r >> 2);
      ob[(size_t)q*DIM_]      = acc_o0[r] + redA[(w4*32 + row)*64 + l31];
      ob[(size_t)q*DIM_ + 32] = acc_o1[r] + redA[(w4*32 + row)*64 + l31 + 32];
    }
  }
#undef STAGE
}

extern "C" void kernel_launch(void* const* d_in, const int* in_sizes, int n_in,
                              void* d_out, int out_size, void* d_ws, size_t ws_size,
                              hipStream_t stream) {
  const float* x  = (const float*)d_in[0];
  const float* Wq = (const float*)d_in[1];
  const float* Wk = (const float*)d_in[2];
  float* out = (float*)d_out;
  char* ws = (char*)d_ws;
  u16* xb  = (u16*)(ws);                      // 8 MiB
  u16* wqb = (u16*)(ws + 8388608);            // 512 KiB
  u16* wkb = (u16*)(ws + 8912896);            // 512 KiB
  u16* qb  = (u16*)(ws + 9437184);            // 8 MiB  [bh][n][64]
  u16* kb  = (u16*)(ws + 17825792);           // 8 MiB
  u16* vt  = (u16*)(ws + 26214400);           // 8 MiB  [bh][d][n]

  k_prep_x<<<dim3(32, 8, 4), 256, 0, stream>>>(x, xb, vt);
  k_convert_w<<<256, 256, 0, stream>>>(Wq, Wk, wqb, wkb);
  k_gemm_qk<<<dim3(64, 4, 2), 256, 0, stream>>>(xb, wqb, wkb, qb, kb);
  k_attn<<<512, 1024, 0, stream>>>(qb, kb, vt, out);
}

// Round 9
// 85.659 us; speedup vs baseline: 3.4794x; 3.4794x over previous
//
#include <hip/hip_runtime.h>
#include <hip/hip_bf16.h>
#include <stdint.h>

#define B_ 4
#define N_ 2048
#define DIM_ 512
#define H_ 8
#define D_ 64
#define M_ (B_*N_)   // 8192

typedef unsigned short u16;
typedef short bf16x8 __attribute__((ext_vector_type(8)));
typedef float f32x4 __attribute__((ext_vector_type(4)));
typedef float f32x16 __attribute__((ext_vector_type(16)));
typedef unsigned short u16x8 __attribute__((ext_vector_type(8)));
typedef unsigned short u16x4 __attribute__((ext_vector_type(4)));

__device__ __forceinline__ u16 f2bf(float f) {
  union { float f; uint32_t u; } v; v.f = f;
  uint32_t r = v.u + 0x7fffu + ((v.u >> 16) & 1u);
  return (u16)(r >> 16);
}

__device__ __forceinline__ void gload_lds16(const void* g, void* l) {
  __builtin_amdgcn_global_load_lds(
      (const __attribute__((address_space(1))) void*)g,
      (__attribute__((address_space(3))) void*)l, 16, 0, 0);
}

__device__ __forceinline__ uint32_t cvt_pk(float a, float b) {
  uint32_t r;
  asm("v_cvt_pk_bf16_f32 %0, %1, %2" : "=v"(r) : "v"(a), "v"(b));
  return r;
}

// swaps upper 32 lanes of a with lower 32 lanes of b
__device__ __forceinline__ void swap32(uint32_t &a, uint32_t &b) {
  asm("v_permlane32_swap_b32 %0, %1" : "+v"(a), "+v"(b));
}

__device__ __forceinline__ bf16x8 mkfrag(uint32_t w0, uint32_t w1, uint32_t w2, uint32_t w3) {
  union { uint32_t u[4]; bf16x8 v; } x;
  x.u[0]=w0; x.u[1]=w1; x.u[2]=w2; x.u[3]=w3;
  return x.v;
}

// ---------------- fused: x -> xb bf16 [8192][512]  AND  x -> vt[bh][d][n] bf16 ----------------
__global__ __launch_bounds__(256) void k_prep_x(const float* __restrict__ x,
                                                u16* __restrict__ xb,
                                                u16* __restrict__ vt) {
  __shared__ float ts[64][65];
  int nt = blockIdx.x;   // 0..31  (n tile of 64)
  int h  = blockIdx.y;   // 0..7
  int b  = blockIdx.z;   // 0..3
  int t = threadIdx.x;
  int n0 = nt * 64;
  int r16 = t >> 4;         // 0..15
  int c4  = (t & 15) * 4;   // 0..60
#pragma unroll
  for (int rep = 0; rep < 4; ++rep) {
    int n_loc = rep*16 + r16;
    size_t row = (size_t)(b*N_ + n0 + n_loc);
    float4 v = *(const float4*)(x + row*DIM_ + h*64 + c4);
    ts[n_loc][c4+0]=v.x; ts[n_loc][c4+1]=v.y; ts[n_loc][c4+2]=v.z; ts[n_loc][c4+3]=v.w;
    u16x4 o; o[0]=f2bf(v.x); o[1]=f2bf(v.y); o[2]=f2bf(v.z); o[3]=f2bf(v.w);
    *(u16x4*)(xb + row*DIM_ + h*64 + c4) = o;
  }
  __syncthreads();
#pragma unroll
  for (int rep = 0; rep < 4; ++rep) {
    int d_loc = rep*16 + r16;
    u16x4 o;
#pragma unroll
    for (int i = 0; i < 4; ++i) o[i] = f2bf(ts[c4+i][d_loc]);
    *(u16x4*)(vt + (size_t)((b*H_+h)*64 + d_loc)*N_ + n0 + c4) = o;
  }
}

// ---------------- convert Wq/Wk -> bf16 ----------------
__global__ __launch_bounds__(256) void k_convert_w(const float* __restrict__ Wq,
                                                   const float* __restrict__ Wk,
                                                   u16* __restrict__ wqb,
                                                   u16* __restrict__ wkb) {
  int t = blockIdx.x * 256 + threadIdx.x;
  int e = t * 8;
  const float* src; u16* dst; int off;
  if (e < DIM_*DIM_) { src = Wq; dst = wqb; off = e; }
  else               { src = Wk; dst = wkb; off = e - DIM_*DIM_; }
  const float4* p = (const float4*)(src + off);
  float4 a = p[0], b = p[1];
  u16x8 o;
  o[0]=f2bf(a.x); o[1]=f2bf(a.y); o[2]=f2bf(a.z); o[3]=f2bf(a.w);
  o[4]=f2bf(b.x); o[5]=f2bf(b.y); o[6]=f2bf(b.z); o[7]=f2bf(b.w);
  *(u16x8*)(dst + off) = o;
}

// ---------------- projection GEMM: [8192x512] = xb @ W^T, store head-major ----------------
// q additionally scaled by 2*log2(e) so attn can use exp2(s) directly.
__global__ __launch_bounds__(256) void k_gemm_qk(const u16* __restrict__ xb,
                                                 const u16* __restrict__ wqb,
                                                 const u16* __restrict__ wkb,
                                                 u16* __restrict__ qb,
                                                 u16* __restrict__ kb) {
  __shared__ __align__(16) u16 As[128*64];
  __shared__ __align__(16) u16 Bs[128*64];
  int mt = blockIdx.x, ntile = blockIdx.y, z = blockIdx.z;
  const u16* Bw = z ? wkb : wqb;
  u16* C = z ? kb : qb;
  float scale = z ? 1.0f : 0.36067376022224085f;   // 0.125 * 2.8853900817779268
  int tid = threadIdx.x, lane = tid & 63, w = tid >> 6;
  int wr = w >> 1, wc = w & 1;
  int lr = lane >> 3, lc8 = lane & 7;
  int l4 = lane >> 4, l15 = lane & 15;

  f32x4 acc[4][4] = {};

  const u16* Abase = xb + (size_t)(mt*128)*DIM_;
  const u16* Bbase = Bw + (size_t)(ntile*128)*DIM_;

  for (int kk = 0; kk < 8; ++kk) {
#pragma unroll
    for (int i = 0; i < 4; ++i) {
      int rowl = w*32 + i*8 + lr;
      int cbs = lc8 ^ (rowl & 7);
      gload_lds16(Abase + (size_t)rowl*DIM_ + kk*64 + cbs*8, As + (w*32 + i*8)*64);
      gload_lds16(Bbase + (size_t)rowl*DIM_ + kk*64 + cbs*8, Bs + (w*32 + i*8)*64);
    }
    __syncthreads();
#pragma unroll
    for (int kc = 0; kc < 2; ++kc) {
      bf16x8 af[4], bfr[4];
#pragma unroll
      for (int i = 0; i < 4; ++i) {
        int row = wr*64 + i*16 + l15;
        int cb = (kc*4 + l4) ^ (row & 7);
        af[i] = *(const bf16x8*)(As + row*64 + cb*8);
      }
#pragma unroll
      for (int j = 0; j < 4; ++j) {
        int row = wc*64 + j*16 + l15;
        int cb = (kc*4 + l4) ^ (row & 7);
        bfr[j] = *(const bf16x8*)(Bs + row*64 + cb*8);
      }
#pragma unroll
      for (int i = 0; i < 4; ++i)
#pragma unroll
        for (int j = 0; j < 4; ++j)
          acc[i][j] = __builtin_amdgcn_mfma_f32_16x16x32_bf16(af[i], bfr[j], acc[i][j], 0, 0, 0);
    }
    __syncthreads();
  }
#pragma unroll
  for (int i = 0; i < 4; ++i) {
#pragma unroll
    for (int j = 0; j < 4; ++j) {
#pragma unroll
      for (int r = 0; r < 4; ++r) {
        int m = mt*128 + wr*64 + i*16 + l4*4 + r;
        int o = ntile*128 + wc*64 + j*16 + l15;
        u16 v = f2bf(acc[i][j][r] * scale);
        C[(size_t)((m >> 11)*H_ + (o >> 6))*(N_*64) + (size_t)(m & (N_-1))*64 + (o & 63)] = v;
      }
    }
  }
}

// ---------------- attention: out = tanh(q k^T) v  (barrier-free main loop) ----------------
// grid 512 blocks (xcd-chunked), 512 threads = 8 waves = 4 qsub x 2 kv-half.
// Each wave owns a PRIVATE single-buffered LDS tile pair (K 4KB + V 4KB) and runs
// its kv sweep with no block barriers: vmcnt(0) -> ds_read frags -> lgkmcnt(0) ->
// issue next stage -> compute (stage latency hidden under tanh/MFMA).
// One __syncthreads before the final 2-way kv reduce (LDS reused).
__global__ __launch_bounds__(512, 4) void k_attn(const u16* __restrict__ qb,
                                                 const u16* __restrict__ kb,
                                                 const u16* __restrict__ vt,
                                                 float* __restrict__ out) {
  __shared__ __align__(16) u16 Tiles[8][4096];   // per-wave 8 KB: K [32][128B] + V [64][64B]
  int wg = blockIdx.x;
  int xcd = wg & 7, local = wg >> 3;       // local 0..63
  int bh = (xcd << 2) | (local >> 4);      // 4 bh per XCD -> K/V L2-resident
  int qt = local & 15;                     // 0..15, 128 q rows
  int tid = threadIdx.x, lane = tid & 63, w = tid >> 6;   // w 0..7
  int w4 = w & 3, grp = w >> 2;            // q sub-tile / kv half
  int l31 = lane & 31, hi = lane >> 5;
  int qrow = qt*128 + w4*32 + l31;

  const char* kbh = (const char*)(kb + (size_t)bh*N_*64);
  const char* vbh = (const char*)(vt + (size_t)bh*64*N_);
  char* myT = (char*)&Tiles[w][0];

  // Q fragments (B-operand rows): Q[q=l31][d = c*16 + hi*8 ..+8]
  const u16* qp = qb + ((size_t)bh*N_ + qrow)*64 + hi*8;
  bf16x8 qf[4];
#pragma unroll
  for (int c = 0; c < 4; ++c) qf[c] = *(const bf16x8*)(qp + c*16);

  // staging lane geometry (wave-private tiles)
  int r8l   = lane >> 3;                          // K row within 8-row chunk
  int ksw16 = ((lane & 7) ^ r8l) * 16;            // K inverse-swizzled src col
  int l4s   = lane >> 2;                          // V row within 16-row chunk
  int vsw16 = ((lane & 3) ^ ((lane >> 3) & 3)) * 16;  // V inverse-swizzled src col
  int kvb = grp * 1024;

#define STAGE(jt_) do { \
    int kv0_ = kvb + (jt_)*32; \
    _Pragma("unroll") \
    for (int i_ = 0; i_ < 4; ++i_) { \
      gload_lds16(kbh + (size_t)(kv0_ + i_*8 + r8l)*128 + ksw16, myT + i_*1024); \
      gload_lds16(vbh + (size_t)(i_*16 + l4s)*(N_*2) + (size_t)kv0_*2 + vsw16, \
                  myT + 4096 + i_*1024); \
    } \
  } while (0)

  int rswk = (l31 & 7) << 4;        // K read swizzle
  int vr   = (l31 >> 1) & 3;        // V read swizzle slot

  f32x16 acc_o0 = {};
  f32x16 acc_o1 = {};

  STAGE(0);

  for (int jt = 0; jt < 32; ++jt) {
    // wait for this tile's staged data (wave-private -> no barrier needed)
    asm volatile("s_waitcnt vmcnt(0)" ::: "memory");
    __builtin_amdgcn_sched_barrier(0);
    // K fragments: K[kv=l31][d = c*16 + hi*8]
    bf16x8 ka[4];
#pragma unroll
    for (int c = 0; c < 4; ++c)
      ka[c] = *(const bf16x8*)(myT + l31*128 + ((c*32 + hi*16) ^ rswk));
    // V fragments: V[d=dh*32+l31][kv slot kc*2+hi]
    bf16x8 vb[2][2];
#pragma unroll
    for (int kc = 0; kc < 2; ++kc)
#pragma unroll
      for (int dh = 0; dh < 2; ++dh)
        vb[kc][dh] = *(const bf16x8*)(myT + 4096 + (dh*32 + l31)*64 + (((kc*2 + hi) ^ vr) << 4));
    asm volatile("s_waitcnt lgkmcnt(0)" ::: "memory");
    __builtin_amdgcn_sched_barrier(0);
    // frags in regs -> safe to overwrite the tile; issue next stage now
    if (jt < 31) STAGE(jt + 1);

    // S^T tile: rows = kv (crow(r,hi)), cols = q (l31)
    f32x16 st = {};
    __builtin_amdgcn_s_setprio(1);
#pragma unroll
    for (int c = 0; c < 4; ++c)
      st = __builtin_amdgcn_mfma_f32_32x32x16_bf16(ka[c], qf[c], st, 0, 0, 0);
    __builtin_amdgcn_s_setprio(0);
    // tanh in-register: t = 1 - 2/(2^s + 1)   (2.885*log2e folded into q)
    float p[16];
#pragma unroll
    for (int r = 0; r < 16; ++r) {
      float e = __builtin_amdgcn_exp2f(st[r]);
      p[r] = 1.0f - 2.0f * __builtin_amdgcn_rcpf(e + 1.0f);
    }
    // pack to PV A-fragments: word w holds kv = ks*16 + hi*8 + {2w,2w+1}
    uint32_t a0 = cvt_pk(p[0], p[1]),   b0 = cvt_pk(p[4], p[5]);
    uint32_t a1 = cvt_pk(p[2], p[3]),   b1 = cvt_pk(p[6], p[7]);
    swap32(a0, b0); swap32(a1, b1);
    uint32_t a2 = cvt_pk(p[8], p[9]),   b2 = cvt_pk(p[12], p[13]);
    uint32_t a3 = cvt_pk(p[10], p[11]), b3 = cvt_pk(p[14], p[15]);
    swap32(a2, b2); swap32(a3, b3);
    bf16x8 pa0 = mkfrag(a0, a1, b0, b1);   // kv 0..15
    bf16x8 pa1 = mkfrag(a2, a3, b2, b3);   // kv 16..31
    // O += P V
    __builtin_amdgcn_s_setprio(1);
    acc_o0 = __builtin_amdgcn_mfma_f32_32x32x16_bf16(pa0, vb[0][0], acc_o0, 0, 0, 0);
    acc_o1 = __builtin_amdgcn_mfma_f32_32x32x16_bf16(pa0, vb[0][1], acc_o1, 0, 0, 0);
    acc_o0 = __builtin_amdgcn_mfma_f32_32x32x16_bf16(pa1, vb[1][0], acc_o0, 0, 0, 0);
    acc_o1 = __builtin_amdgcn_mfma_f32_32x32x16_bf16(pa1, vb[1][1], acc_o1, 0, 0, 0);
    __builtin_amdgcn_s_setprio(0);
  }

  // 2-way kv combine via reused tile LDS (one barrier pair)
  __syncthreads();
  float* red = (float*)&Tiles[0][0];   // [4 w4][32][64] f32 = 32 KB
  if (grp == 1) {
#pragma unroll
    for (int r = 0; r < 16; ++r) {
      int row = 4*hi + (r & 3) + 8*(r >> 2);
      red[(w4*32 + row)*64 + l31]      = acc_o0[r];
      red[(w4*32 + row)*64 + l31 + 32] = acc_o1[r];
    }
  }
  __syncthreads();
  if (grp == 0) {
    int b = bh >> 3, h = bh & 7;
    int q0 = qt*128 + w4*32 + 4*hi;
    float* ob = out + (size_t)b*N_*DIM_ + h*64 + l31;
#pragma unroll
    for (int r = 0; r < 16; ++r) {
      int row = 4*hi + (r & 3) + 8*(r >> 2);
      int q = q0 + (r & 3) + 8*(r >> 2);
      ob[(size_t)q*DIM_]      = acc_o0[r] + red[(w4*32 + row)*64 + l31];
      ob[(size_t)q*DIM_ + 32] = acc_o1[r] + red[(w4*32 + row)*64 + l31 + 32];
    }
  }
#undef STAGE
}

extern "C" void kernel_launch(void* const* d_in, const int* in_sizes, int n_in,
                              void* d_out, int out_size, void* d_ws, size_t ws_size,
                              hipStream_t stream) {
  const float* x  = (const float*)d_in[0];
  const float* Wq = (const float*)d_in[1];
  const float* Wk = (const float*)d_in[2];
  float* out = (float*)d_out;
  char* ws = (char*)d_ws;
  u16* xb  = (u16*)(ws);                      // 8 MiB
  u16* wqb = (u16*)(ws + 8388608);            // 512 KiB
  u16* wkb = (u16*)(ws + 8912896);            // 512 KiB
  u16* qb  = (u16*)(ws + 9437184);            // 8 MiB  [bh][n][64]
  u16* kb  = (u16*)(ws + 17825792);           // 8 MiB
  u16* vt  = (u16*)(ws + 26214400);           // 8 MiB  [bh][d][n]

  k_prep_x<<<dim3(32, 8, 4), 256, 0, stream>>>(x, xb, vt);
  k_convert_w<<<256, 256, 0, stream>>>(Wq, Wk, wqb, wkb);
  k_gemm_qk<<<dim3(64, 4, 2), 256, 0, stream>>>(xb, wqb, wkb, qb, kb);
  k_attn<<<512, 512, 0, stream>>>(qb, kb, vt, out);
}

// Round 10
// 80.390 us; speedup vs baseline: 3.7074x; 1.0655x over previous
//
#include <hip/hip_runtime.h>
#include <hip/hip_bf16.h>
#include <stdint.h>

#define B_ 4
#define N_ 2048
#define DIM_ 512
#define H_ 8
#define D_ 64
#define M_ (B_*N_)   // 8192

typedef unsigned short u16;
typedef short bf16x8 __attribute__((ext_vector_type(8)));
typedef float f32x4 __attribute__((ext_vector_type(4)));
typedef float f32x16 __attribute__((ext_vector_type(16)));
typedef unsigned short u16x8 __attribute__((ext_vector_type(8)));
typedef unsigned short u16x4 __attribute__((ext_vector_type(4)));

__device__ __forceinline__ u16 f2bf(float f) {
  union { float f; uint32_t u; } v; v.f = f;
  uint32_t r = v.u + 0x7fffu + ((v.u >> 16) & 1u);
  return (u16)(r >> 16);
}

__device__ __forceinline__ void gload_lds16(const void* g, void* l) {
  __builtin_amdgcn_global_load_lds(
      (const __attribute__((address_space(1))) void*)g,
      (__attribute__((address_space(3))) void*)l, 16, 0, 0);
}

__device__ __forceinline__ uint32_t cvt_pk(float a, float b) {
  uint32_t r;
  asm("v_cvt_pk_bf16_f32 %0, %1, %2" : "=v"(r) : "v"(a), "v"(b));
  return r;
}

// swaps upper 32 lanes of a with lower 32 lanes of b
__device__ __forceinline__ void swap32(uint32_t &a, uint32_t &b) {
  asm("v_permlane32_swap_b32 %0, %1" : "+v"(a), "+v"(b));
}

__device__ __forceinline__ bf16x8 mkfrag(uint32_t w0, uint32_t w1, uint32_t w2, uint32_t w3) {
  union { uint32_t u[4]; bf16x8 v; } x;
  x.u[0]=w0; x.u[1]=w1; x.u[2]=w2; x.u[3]=w3;
  return x.v;
}

// ---------------- fused: x -> xb bf16 [8192][512]  AND  x -> vtp[bh][kv>>3][d][kv&7] ----------------
__global__ __launch_bounds__(256) void k_prep_x(const float* __restrict__ x,
                                                u16* __restrict__ xb,
                                                u16* __restrict__ vtp) {
  __shared__ float ts[64][65];
  int nt = blockIdx.x;   // 0..31  (n tile of 64)
  int h  = blockIdx.y;   // 0..7
  int b  = blockIdx.z;   // 0..3
  int t = threadIdx.x;
  int n0 = nt * 64;
  int r16 = t >> 4;         // 0..15
  int c4  = (t & 15) * 4;   // 0..60
#pragma unroll
  for (int rep = 0; rep < 4; ++rep) {
    int n_loc = rep*16 + r16;
    size_t row = (size_t)(b*N_ + n0 + n_loc);
    float4 v = *(const float4*)(x + row*DIM_ + h*64 + c4);
    ts[n_loc][c4+0]=v.x; ts[n_loc][c4+1]=v.y; ts[n_loc][c4+2]=v.z; ts[n_loc][c4+3]=v.w;
    u16x4 o; o[0]=f2bf(v.x); o[1]=f2bf(v.y); o[2]=f2bf(v.z); o[3]=f2bf(v.w);
    *(u16x4*)(xb + row*DIM_ + h*64 + c4) = o;
  }
  __syncthreads();
#pragma unroll
  for (int rep = 0; rep < 4; ++rep) {
    int d_loc = rep*16 + r16;
    u16x4 o;
#pragma unroll
    for (int i = 0; i < 4; ++i) o[i] = f2bf(ts[c4+i][d_loc]);
    int n = n0 + c4;
    // vtp[bh][n>>3][d][n&7]
    *(u16x4*)(vtp + (size_t)(b*H_+h)*131072 + (size_t)(n >> 3)*512 + d_loc*8 + (n & 7)) = o;
  }
}

// ---------------- convert Wq/Wk -> bf16 ----------------
__global__ __launch_bounds__(256) void k_convert_w(const float* __restrict__ Wq,
                                                   const float* __restrict__ Wk,
                                                   u16* __restrict__ wqb,
                                                   u16* __restrict__ wkb) {
  int t = blockIdx.x * 256 + threadIdx.x;
  int e = t * 8;
  const float* src; u16* dst; int off;
  if (e < DIM_*DIM_) { src = Wq; dst = wqb; off = e; }
  else               { src = Wk; dst = wkb; off = e - DIM_*DIM_; }
  const float4* p = (const float4*)(src + off);
  float4 a = p[0], b = p[1];
  u16x8 o;
  o[0]=f2bf(a.x); o[1]=f2bf(a.y); o[2]=f2bf(a.z); o[3]=f2bf(a.w);
  o[4]=f2bf(b.x); o[5]=f2bf(b.y); o[6]=f2bf(b.z); o[7]=f2bf(b.w);
  *(u16x8*)(dst + off) = o;
}

// ---------------- projection GEMM: [8192x512] = xb @ W^T ----------------
// q (z=0): head-major [bh][n][64], pre-scaled by 0.125*2*log2(e).
// k (z=1): fragment-native kbp[bh][d>>3][kv][d&7].
__global__ __launch_bounds__(256) void k_gemm_qk(const u16* __restrict__ xb,
                                                 const u16* __restrict__ wqb,
                                                 const u16* __restrict__ wkb,
                                                 u16* __restrict__ qb,
                                                 u16* __restrict__ kb) {
  __shared__ __align__(16) u16 As[128*64];
  __shared__ __align__(16) u16 Bs[128*64];
  int mt = blockIdx.x, ntile = blockIdx.y, z = blockIdx.z;
  const u16* Bw = z ? wkb : wqb;
  u16* C = z ? kb : qb;
  float scale = z ? 1.0f : 0.36067376022224085f;   // 0.125 * 2.8853900817779268
  int tid = threadIdx.x, lane = tid & 63, w = tid >> 6;
  int wr = w >> 1, wc = w & 1;
  int lr = lane >> 3, lc8 = lane & 7;
  int l4 = lane >> 4, l15 = lane & 15;

  f32x4 acc[4][4] = {};

  const u16* Abase = xb + (size_t)(mt*128)*DIM_;
  const u16* Bbase = Bw + (size_t)(ntile*128)*DIM_;

  for (int kk = 0; kk < 8; ++kk) {
#pragma unroll
    for (int i = 0; i < 4; ++i) {
      int rowl = w*32 + i*8 + lr;
      int cbs = lc8 ^ (rowl & 7);
      gload_lds16(Abase + (size_t)rowl*DIM_ + kk*64 + cbs*8, As + (w*32 + i*8)*64);
      gload_lds16(Bbase + (size_t)rowl*DIM_ + kk*64 + cbs*8, Bs + (w*32 + i*8)*64);
    }
    __syncthreads();
#pragma unroll
    for (int kc = 0; kc < 2; ++kc) {
      bf16x8 af[4], bfr[4];
#pragma unroll
      for (int i = 0; i < 4; ++i) {
        int row = wr*64 + i*16 + l15;
        int cb = (kc*4 + l4) ^ (row & 7);
        af[i] = *(const bf16x8*)(As + row*64 + cb*8);
      }
#pragma unroll
      for (int j = 0; j < 4; ++j) {
        int row = wc*64 + j*16 + l15;
        int cb = (kc*4 + l4) ^ (row & 7);
        bfr[j] = *(const bf16x8*)(Bs + row*64 + cb*8);
      }
#pragma unroll
      for (int i = 0; i < 4; ++i)
#pragma unroll
        for (int j = 0; j < 4; ++j)
          acc[i][j] = __builtin_amdgcn_mfma_f32_16x16x32_bf16(af[i], bfr[j], acc[i][j], 0, 0, 0);
    }
    __syncthreads();
  }
#pragma unroll
  for (int i = 0; i < 4; ++i) {
#pragma unroll
    for (int j = 0; j < 4; ++j) {
#pragma unroll
      for (int r = 0; r < 4; ++r) {
        int m = mt*128 + wr*64 + i*16 + l4*4 + r;
        int o = ntile*128 + wc*64 + j*16 + l15;
        u16 v = f2bf(acc[i][j][r] * scale);
        int bh = (m >> 11)*H_ + (o >> 6);
        int kv = m & (N_-1);
        int d  = o & 63;
        if (z) {
          // kbp[bh][d>>3][kv][d&7]
          C[(size_t)bh*131072 + (size_t)(d >> 3)*16384 + (size_t)kv*8 + (d & 7)] = v;
        } else {
          C[(size_t)bh*131072 + (size_t)kv*64 + d] = v;
        }
      }
    }
  }
}

// ---------------- attention: out = tanh(q k^T) v  (LDS-free main loop) ----------------
// grid 512 blocks (xcd-chunked: xcd owns bh[4x,4x+4)), 512 threads = 8 waves
// = 4 qsub x 2 kv-half. All K/V fragment loads are coalesced global b128 reads
// from fragment-native layouts (L2-resident per XCD, L1 absorbs q-wave reuse).
// No LDS, no barriers in the loop; one sync pair for the 2-way kv reduce.
__global__ __launch_bounds__(512, 4) void k_attn(const u16* __restrict__ qb,
                                                 const u16* __restrict__ kbp,
                                                 const u16* __restrict__ vtp,
                                                 float* __restrict__ out) {
  __shared__ float red[4][32][64];   // 32 KB, epilogue reduce only
  int wg = blockIdx.x;
  int xcd = wg & 7, local = wg >> 3;       // local 0..63
  int bh = (xcd << 2) | (local >> 4);      // 4 bh per XCD -> K/V L2-resident
  int qt = local & 15;                     // 0..15, 128 q rows
  int tid = threadIdx.x, lane = tid & 63, w = tid >> 6;   // w 0..7
  int w4 = w & 3, grp = w >> 2;            // q sub-tile / kv half
  int l31 = lane & 31, hi = lane >> 5;
  int qrow = qt*128 + w4*32 + l31;

  // Q fragments (B-operand rows): Q[q=l31][d = c*16 + hi*8 ..+8]
  const u16* qp = qb + ((size_t)bh*N_ + qrow)*64 + hi*8;
  bf16x8 qf[4];
#pragma unroll
  for (int c = 0; c < 4; ++c) qf[c] = *(const bf16x8*)(qp + c*16);

  int kvb = grp * 1024;
  // K frag base: lane=kv, d-slice group g = c*2+hi
  const u16* kp = kbp + (size_t)bh*131072 + (size_t)hi*16384 + (size_t)(kvb + l31)*8;
  // V frag base: lane=d, kv-slice group gv = (kv0>>3) + kc*2 + hi
  const u16* vp = vtp + (size_t)bh*131072 + (size_t)((kvb >> 3) + hi)*512 + (size_t)l31*8;

  f32x16 acc_o0 = {};
  f32x16 acc_o1 = {};

  for (int jt = 0; jt < 32; ++jt) {
    // K fragments: K[kv = kv0+l31][d = c*16 + hi*8]  (coalesced b128)
    bf16x8 ka[4];
#pragma unroll
    for (int c = 0; c < 4; ++c)
      ka[c] = *(const bf16x8*)(kp + jt*256 + c*32768);
    // V fragments: B[k=kv slice (kc*2+hi)*8][col=d=dh*32+l31]  (coalesced b128)
    bf16x8 vb[2][2];
#pragma unroll
    for (int kc = 0; kc < 2; ++kc)
#pragma unroll
      for (int dh = 0; dh < 2; ++dh)
        vb[kc][dh] = *(const bf16x8*)(vp + jt*2048 + kc*1024 + dh*256);

    // S^T tile: rows = kv (crow(r,hi)), cols = q (l31)
    f32x16 st = {};
    __builtin_amdgcn_s_setprio(1);
#pragma unroll
    for (int c = 0; c < 4; ++c)
      st = __builtin_amdgcn_mfma_f32_32x32x16_bf16(ka[c], qf[c], st, 0, 0, 0);
    __builtin_amdgcn_s_setprio(0);
    // tanh in-register: t = 1 - 2/(2^s + 1)   (2*log2e folded into q scale)
    float p[16];
#pragma unroll
    for (int r = 0; r < 16; ++r) {
      float e = __builtin_amdgcn_exp2f(st[r]);
      p[r] = 1.0f - 2.0f * __builtin_amdgcn_rcpf(e + 1.0f);
    }
    // pack to PV A-fragments: word w holds kv = ks*16 + hi*8 + {2w,2w+1}
    uint32_t a0 = cvt_pk(p[0], p[1]),   b0 = cvt_pk(p[4], p[5]);
    uint32_t a1 = cvt_pk(p[2], p[3]),   b1 = cvt_pk(p[6], p[7]);
    swap32(a0, b0); swap32(a1, b1);
    uint32_t a2 = cvt_pk(p[8], p[9]),   b2 = cvt_pk(p[12], p[13]);
    uint32_t a3 = cvt_pk(p[10], p[11]), b3 = cvt_pk(p[14], p[15]);
    swap32(a2, b2); swap32(a3, b3);
    bf16x8 pa0 = mkfrag(a0, a1, b0, b1);   // kv 0..15
    bf16x8 pa1 = mkfrag(a2, a3, b2, b3);   // kv 16..31
    // O += P V
    __builtin_amdgcn_s_setprio(1);
    acc_o0 = __builtin_amdgcn_mfma_f32_32x32x16_bf16(pa0, vb[0][0], acc_o0, 0, 0, 0);
    acc_o1 = __builtin_amdgcn_mfma_f32_32x32x16_bf16(pa0, vb[0][1], acc_o1, 0, 0, 0);
    acc_o0 = __builtin_amdgcn_mfma_f32_32x32x16_bf16(pa1, vb[1][0], acc_o0, 0, 0, 0);
    acc_o1 = __builtin_amdgcn_mfma_f32_32x32x16_bf16(pa1, vb[1][1], acc_o1, 0, 0, 0);
    __builtin_amdgcn_s_setprio(0);
  }

  // 2-way kv combine via LDS (one barrier pair)
  if (grp == 1) {
#pragma unroll
    for (int r = 0; r < 16; ++r) {
      int row = 4*hi + (r & 3) + 8*(r >> 2);
      red[w4][row][l31]      = acc_o0[r];
      red[w4][row][l31 + 32] = acc_o1[r];
    }
  }
  __syncthreads();
  if (grp == 0) {
    int b = bh >> 3, h = bh & 7;
    int q0 = qt*128 + w4*32 + 4*hi;
    float* ob = out + (size_t)b*N_*DIM_ + h*64 + l31;
#pragma unroll
    for (int r = 0; r < 16; ++r) {
      int row = 4*hi + (r & 3) + 8*(r >> 2);
      int q = q0 + (r & 3) + 8*(r >> 2);
      ob[(size_t)q*DIM_]      = acc_o0[r] + red[w4][row][l31];
      ob[(size_t)q*DIM_ + 32] = acc_o1[r] + red[w4][row][l31 + 32];
    }
  }
}

extern "C" void kernel_launch(void* const* d_in, const int* in_sizes, int n_in,
                              void* d_out, int out_size, void* d_ws, size_t ws_size,
                              hipStream_t stream) {
  const float* x  = (const float*)d_in[0];
  const float* Wq = (const float*)d_in[1];
  const float* Wk = (const float*)d_in[2];
  float* out = (float*)d_out;
  char* ws = (char*)d_ws;
  u16* xb  = (u16*)(ws);                      // 8 MiB
  u16* wqb = (u16*)(ws + 8388608);            // 512 KiB
  u16* wkb = (u16*)(ws + 8912896);            // 512 KiB
  u16* qb  = (u16*)(ws + 9437184);            // 8 MiB  [bh][n][64]
  u16* kbp = (u16*)(ws + 17825792);           // 8 MiB  [bh][d>>3][kv][d&7]
  u16* vtp = (u16*)(ws + 26214400);           // 8 MiB  [bh][kv>>3][d][kv&7]

  k_prep_x<<<dim3(32, 8, 4), 256, 0, stream>>>(x, xb, vtp);
  k_convert_w<<<256, 256, 0, stream>>>(Wq, Wk, wqb, wkb);
  k_gemm_qk<<<dim3(64, 4, 2), 256, 0, stream>>>(xb, wqb, wkb, qb, kbp);
  k_attn<<<512, 512, 0, stream>>>(qb, kbp, vtp, out);
}